// Round 2
// baseline (3828.838 us; speedup 1.0000x reference)
//
#include <hip/hip_runtime.h>

// EIRNN: B=256,T=512,I=128,H=512,O=64; alpha=0.2, softplus beta=8, thresh=20.
// R3: collapse 8-way H-sharding to 2-way with 1024-thread blocks (16 waves).
// Rationale (R2 post-mortem): per-step time 6240cy was ~90% wait; with 8
// shards each block waits on the MAX over 7 producers' store-visibility +
// a full poll-retry period. Batch rows are embarrassingly parallel -- the
// only reason for 8 shards was W_hh register capacity per 256-thread block.
// A 16-wave block holds 256 of 512 h-cols (64 VGPR of B-frags per wave,
// same as before), so each group is TWO blocks: one partner to wait on,
// half the h-exchange short-circuits through LDS.
// Loop is restructured so the first poll round is issued immediately after
// the tagged h-store; x-staging and the y-readout (MFMA + atomicAdd) then
// execute INSIDE the poll-latency window instead of serially before it.
// Exchange stays R2's single-hop tagged u64 {hi: tag=t+1, lo: 2xf16}:
// fire-and-forget stores, per-word freshness, parity double-buffer makes
// overwrite-before-consume impossible (producer reaches t+2 only after its
// own gather of h_{t+1}, which postdates every consumer's poll of h_t).

#define BB 256
#define TT 512
#define II 128
#define HH 512
#define OO 64
#define RG 16   // batch rows per group
#define JC 256  // h-columns per block
#define NG 16   // groups
#define NC 2    // blocks per group

typedef _Float16 f16;
typedef f16 f16x8 __attribute__((ext_vector_type(8)));
typedef float f32x4 __attribute__((ext_vector_type(4)));

__global__ __launch_bounds__(1024, 1)
void eirnn_persist(const float* __restrict__ x,
                   const float* __restrict__ Wxh,
                   const float* __restrict__ Whh,
                   const float* __restrict__ bh,
                   const float* __restrict__ Wout,
                   const float* __restrict__ bout,
                   float* __restrict__ yout,
                   unsigned long long* __restrict__ hbuf) // 2 * (B*H/2) tagged u64
{
    const int tid  = threadIdx.x;
    const int bid  = blockIdx.x;
    const int wave = tid >> 6;        // 0..15
    const int lane = tid & 63;
    const int quad = lane >> 4;
    const int l16  = lane & 15;
    const int r    = bid >> 1;        // group
    const int c    = bid & 1;         // half (0: cols 0..255, 1: cols 256..511)
    const int rowbase = r * RG;
    const int jbase   = c * JC;
    const int myrow   = wave * 16 + l16;   // 0..255 within block's col range

    __shared__ __align__(16) f16 hg[2][RG][HH + 8];   // full h_t, parity dbuf
    __shared__ __align__(16) f16 xsh[2][RG][II + 8];  // x_t, parity dbuf

    // ---- one-time: weight shards -> constant register B-fragments ----
    // B-frag: lane holds BT[n=lane&15][k=quad*8+j], j=0..7 (verified R0)
    f16x8 bf[16];   // W_hh: 16 cols (this wave), K=512 -> 16 k-steps
    f16x8 xbf[4];   // W_xh: 16 cols, K=128 -> 4 k-steps
    f16x8 bfo[2];   // W_out: n-chunk wave&3, K-chunk wave>>2 (64 of block's 256)
    const int koff = c * 256 + (wave >> 2) * 64;   // readout K offset
    const int ocol = (wave & 3) * 16 + l16;        // readout output col
    {
        const float* wp = Whh + (size_t)(jbase + myrow) * HH + quad * 8;
        #pragma unroll
        for (int ks = 0; ks < 16; ++ks) {
            float4 u = *(const float4*)(wp + ks * 32);
            float4 v = *(const float4*)(wp + ks * 32 + 4);
            f16x8 tv;
            tv[0]=(f16)u.x; tv[1]=(f16)u.y; tv[2]=(f16)u.z; tv[3]=(f16)u.w;
            tv[4]=(f16)v.x; tv[5]=(f16)v.y; tv[6]=(f16)v.z; tv[7]=(f16)v.w;
            bf[ks] = tv;
        }
        const float* wq = Wxh + (size_t)(jbase + myrow) * II + quad * 8;
        #pragma unroll
        for (int ks = 0; ks < 4; ++ks) {
            float4 u = *(const float4*)(wq + ks * 32);
            float4 v = *(const float4*)(wq + ks * 32 + 4);
            f16x8 tv;
            tv[0]=(f16)u.x; tv[1]=(f16)u.y; tv[2]=(f16)u.z; tv[3]=(f16)u.w;
            tv[4]=(f16)v.x; tv[5]=(f16)v.y; tv[6]=(f16)v.z; tv[7]=(f16)v.w;
            xbf[ks] = tv;
        }
        const float* wo = Wout + (size_t)ocol * HH + koff + quad * 8;
        #pragma unroll
        for (int ks = 0; ks < 2; ++ks) {
            float4 u = *(const float4*)(wo + ks * 32);
            float4 v = *(const float4*)(wo + ks * 32 + 4);
            f16x8 tv;
            tv[0]=(f16)u.x; tv[1]=(f16)u.y; tv[2]=(f16)u.z; tv[3]=(f16)u.w;
            tv[4]=(f16)v.x; tv[5]=(f16)v.y; tv[6]=(f16)v.z; tv[7]=(f16)v.w;
            bfo[ks] = tv;
        }
    }
    const float biash = bh[jbase + myrow];
    // bias added exactly once: block c==0, K-chunk 0 waves
    const float biaso = (c == 0 && (wave >> 2) == 0) ? bout[ocol] : 0.0f;

    // zero hg[0] (t=0 uses h_0 = 0; hg[1] fully written during iter 0)
    for (int p4 = tid; p4 < RG * (HH + 8) / 2; p4 += 1024)
        ((unsigned int*)hg)[p4] = 0u;

    // stage x_0 directly; prefetch x_1 into regs (tid<512: 16 rows x 128 cols)
    float4 xpf;
    if (tid < 512) {
        float4 v = ((const float4*)(x + ((size_t)(rowbase + (tid >> 5)) * TT + 0) * II))[tid & 31];
        f16* d = &xsh[0][tid >> 5][(tid & 31) * 4];
        d[0]=(f16)v.x; d[1]=(f16)v.y; d[2]=(f16)v.z; d[3]=(f16)v.w;
        xpf = ((const float4*)(x + ((size_t)(rowbase + (tid >> 5)) * TT + 1) * II))[tid & 31];
    }

    // fp32 integrator state: lane owns h[m=quad*4+reg][jbase+myrow]
    float hreg[4] = {0.f, 0.f, 0.f, 0.f};

    // poll geometry: thread owns partner u64-col pj at rows prow, prow+8
    const int prow = tid >> 7;                     // 0..7
    const int pj   = (1 - c) * 128 + (tid & 127);  // global u64 col in partner half

    for (int t = 0; t < TT; ++t) {
        const int p  = t & 1;
        const int pn = p ^ 1;
        __syncthreads();   // hg[p]=h_t full, xsh[p]=x_t (only barrier per step)

        // ---- pre = h_t.W_hh^T + x_t.W_xh^T + b_h ----
        f32x4 acc0 = {0.f,0.f,0.f,0.f}, acc1 = {0.f,0.f,0.f,0.f};
        #pragma unroll
        for (int ks = 0; ks < 16; ks += 2) {
            f16x8 a0 = *(const f16x8*)&hg[p][l16][ks * 32 + quad * 8];
            f16x8 a1 = *(const f16x8*)&hg[p][l16][(ks + 1) * 32 + quad * 8];
            acc0 = __builtin_amdgcn_mfma_f32_16x16x32_f16(a0, bf[ks], acc0, 0, 0, 0);
            acc1 = __builtin_amdgcn_mfma_f32_16x16x32_f16(a1, bf[ks + 1], acc1, 0, 0, 0);
        }
        #pragma unroll
        for (int ks = 0; ks < 4; ks += 2) {
            f16x8 a0 = *(const f16x8*)&xsh[p][l16][ks * 32 + quad * 8];
            f16x8 a1 = *(const f16x8*)&xsh[p][l16][(ks + 1) * 32 + quad * 8];
            acc0 = __builtin_amdgcn_mfma_f32_16x16x32_f16(a0, xbf[ks], acc0, 0, 0, 0);
            acc1 = __builtin_amdgcn_mfma_f32_16x16x32_f16(a1, xbf[ks + 1], acc1, 0, 0, 0);
        }

        // ---- phi + leaky update; pack pairs; fire-and-forget tagged u64 ----
        unsigned long long* dst64 = hbuf + (size_t)pn * (BB * HH / 2);
        const unsigned long long tagw = ((unsigned long long)(unsigned)(t + 1)) << 32;
        unsigned int hb[4];
        #pragma unroll
        for (int reg = 0; reg < 4; ++reg) {
            float pre = acc0[reg] + acc1[reg] + biash;
            float z = 8.f * pre;
            float ph = (z > 20.f) ? pre : (__logf(1.f + __expf(z)) * 0.125f);
            float hn = 0.8f * hreg[reg] + 0.2f * ph;
            hreg[reg] = hn;
            hb[reg] = (unsigned int)__builtin_bit_cast(unsigned short, (f16)hn);
        }
        #pragma unroll
        for (int reg = 0; reg < 4; ++reg) {
            unsigned int ob = (unsigned int)__shfl_xor((int)hb[reg], 1, 64);
            if ((lane & 1) == 0) {
                unsigned int pair = hb[reg] | (ob << 16);
                size_t eidx = (size_t)(rowbase + quad * 4 + reg) * HH + jbase + myrow;
                __hip_atomic_store(dst64 + (eidx >> 1), tagw | (unsigned long long)pair,
                                   __ATOMIC_RELAXED, __HIP_MEMORY_SCOPE_AGENT);
                // own-half short-circuit into next-parity LDS buffer
                *(unsigned int*)&hg[pn][quad * 4 + reg][jbase + myrow] = pair;
            }
        }

        // ---- issue poll round 1 NOW; x-stage + readout run inside the wait ----
        const unsigned long long* psrc = hbuf + (size_t)pn * (BB * HH / 2)
                                       + (size_t)rowbase * (HH / 2) + pj;
        unsigned long long pv0 = __hip_atomic_load(psrc + (size_t)prow * (HH / 2),
                                                   __ATOMIC_RELAXED, __HIP_MEMORY_SCOPE_AGENT);
        unsigned long long pv1 = __hip_atomic_load(psrc + (size_t)(prow + 8) * (HH / 2),
                                                   __ATOMIC_RELAXED, __HIP_MEMORY_SCOPE_AGENT);
        asm volatile("" ::: "memory");   // pin the load issue before the work below

        // ---- stage x_{t+1}; prefetch x_{t+2} ----
        if (t + 1 < TT && tid < 512) {
            f16* d = &xsh[pn][tid >> 5][(tid & 31) * 4];
            d[0]=(f16)xpf.x; d[1]=(f16)xpf.y; d[2]=(f16)xpf.z; d[3]=(f16)xpf.w;
            if (t + 2 < TT)
                xpf = ((const float4*)(x + ((size_t)(rowbase + (tid >> 5)) * TT + (t + 2)) * II))[tid & 31];
        }

        // ---- readout y_{t-1} = h_t[:, koff:koff+64] . W_out^T (K-split x4x2) ----
        if (t >= 1) {
            f32x4 ya = {0.f,0.f,0.f,0.f};
            f16x8 a0 = *(const f16x8*)&hg[p][l16][koff + quad * 8];
            f16x8 a1 = *(const f16x8*)&hg[p][l16][koff + 32 + quad * 8];
            ya = __builtin_amdgcn_mfma_f32_16x16x32_f16(a0, bfo[0], ya, 0, 0, 0);
            ya = __builtin_amdgcn_mfma_f32_16x16x32_f16(a1, bfo[1], ya, 0, 0, 0);
            #pragma unroll
            for (int reg = 0; reg < 4; ++reg)
                atomicAdd(yout + ((size_t)(rowbase + quad * 4 + reg) * TT + (t - 1)) * OO + ocol,
                          ya[reg] + biaso);
        }

        // ---- complete poll: per-word freshness, payload rides with tag ----
        {
            const unsigned int tg = (unsigned)(t + 1);
            while ((unsigned)(pv0 >> 32) != tg || (unsigned)(pv1 >> 32) != tg) {
                if ((unsigned)(pv0 >> 32) != tg)
                    pv0 = __hip_atomic_load(psrc + (size_t)prow * (HH / 2),
                                            __ATOMIC_RELAXED, __HIP_MEMORY_SCOPE_AGENT);
                if ((unsigned)(pv1 >> 32) != tg)
                    pv1 = __hip_atomic_load(psrc + (size_t)(prow + 8) * (HH / 2),
                                            __ATOMIC_RELAXED, __HIP_MEMORY_SCOPE_AGENT);
            }
            *(unsigned int*)&hg[pn][prow][pj * 2]     = (unsigned int)pv0;
            *(unsigned int*)&hg[pn][prow + 8][pj * 2] = (unsigned int)pv1;
        }
    }

    // ---- epilogue: y_{TT-1} from h_TT (hg[TT&1 = 0]) ----
    __syncthreads();
    {
        f32x4 ya = {0.f,0.f,0.f,0.f};
        f16x8 a0 = *(const f16x8*)&hg[0][l16][koff + quad * 8];
        f16x8 a1 = *(const f16x8*)&hg[0][l16][koff + 32 + quad * 8];
        ya = __builtin_amdgcn_mfma_f32_16x16x32_f16(a0, bfo[0], ya, 0, 0, 0);
        ya = __builtin_amdgcn_mfma_f32_16x16x32_f16(a1, bfo[1], ya, 0, 0, 0);
        #pragma unroll
        for (int reg = 0; reg < 4; ++reg)
            atomicAdd(yout + ((size_t)(rowbase + quad * 4 + reg) * TT + (TT - 1)) * OO + ocol,
                      ya[reg] + biaso);
    }
}

extern "C" void kernel_launch(void* const* d_in, const int* in_sizes, int n_in,
                              void* d_out, int out_size, void* d_ws, size_t ws_size,
                              hipStream_t stream)
{
    const float* x    = (const float*)d_in[0];
    const float* Wxh  = (const float*)d_in[1];
    const float* Whh  = (const float*)d_in[2];
    const float* bh   = (const float*)d_in[3];
    const float* Wout = (const float*)d_in[4];
    const float* bout = (const float*)d_in[5];
    float* yout = (float*)d_out;

    unsigned long long* hbuf = (unsigned long long*)d_ws;
    const size_t hbuf_bytes = (size_t)2 * BB * (HH / 2) * sizeof(unsigned long long); // 1 MB

    if (ws_size < hbuf_bytes) return;

    hipMemsetAsync(hbuf, 0, hbuf_bytes, stream);          // tags start 0; expected 1..512
    hipMemsetAsync(yout, 0, (size_t)out_size * sizeof(float), stream); // atomic targets

    // 32 blocks x 1024 threads (16 waves, 4/SIMD, ~42KB LDS, VGPR<=128 forced).
    eirnn_persist<<<dim3(NG * NC), dim3(1024), 0, stream>>>(
        x, Wxh, Whh, bh, Wout, bout, yout, hbuf);
}

// Round 5
// 2018.117 us; speedup vs baseline: 1.8972x; 1.8972x over previous
//
#include <hip/hip_runtime.h>

// EIRNN: B=256,T=512,I=128,H=512,O=64; alpha=0.2, softplus beta=8, thresh=20.
// R6 = R2 (1340us proven) + ONE delta: polls use sc0-only loads (L1-bypass,
// L2-servable) instead of agent atomic loads (sc0+sc1, forced to IF$).
// R4/R5 post-mortem: both hung identically. fetch_add(p,0) is an idempotent
// RMW -> LLVM rewrites to an atomic load; at workgroup scope that is a plain
// global_load (no sc0) which can be served by a stale L1 line FOREVER ->
// infinite spin. Lesson: one unproven primitive per round, deadlock-proof
// by construction.
// R6 protocol: producer side is EXACTLY R2 (agent/sc1 tagged-u64 fire-and-
// forget stores -- write-through updates the XCD's own L2 en route to IF$).
// Consumer polls with inline-asm `global_load_dwordx2 ... sc0`: bypasses L1,
// served by the XCD L2 (~200-300cy) when producer is co-located on the same
// XCD -- which the bid mapping arranges (xcd=bid&7 round-robin heuristic;
// perf-only assumption). Guaranteed progress WITHOUT any placement
// assumption: every 4th retry round falls back to the R2 agent load
// (sc0+sc1, IF$-served), which R2 proved always observes the store. So
// worst case = R2 latency + small constant; best case = L2 latency.
// Everything else (exchange format, parity double-buffer, LDS short-circuit,
// readout atomicAdd, launch config) is byte-identical to R2.

#define BB 256
#define TT 512
#define II 128
#define HH 512
#define OO 64
#define RG 16   // batch rows per row-group
#define JC 64   // h-columns per shard block
#define NG 16   // row-groups
#define NC 8    // shard blocks per group
#define NB (NG * NC)

typedef _Float16 f16;
typedef f16 f16x8 __attribute__((ext_vector_type(8)));
typedef float f32x4 __attribute__((ext_vector_type(4)));

__global__ __launch_bounds__(256, 1)
void eirnn_persist(const float* __restrict__ x,
                   const float* __restrict__ Wxh,
                   const float* __restrict__ Whh,
                   const float* __restrict__ bh,
                   const float* __restrict__ Wout,
                   const float* __restrict__ bout,
                   float* __restrict__ yout,
                   unsigned long long* __restrict__ hbuf) // 2*(B*H/2) tagged u64
{
    const int tid  = threadIdx.x;
    const int bid  = blockIdx.x;
    const int wave = tid >> 6;
    const int lane = tid & 63;
    const int quad = lane >> 4;
    const int l16  = lane & 15;
    // XCD-clustered mapping (PERF HEURISTIC ONLY: presumed round-robin
    // dispatch xcd=bid&7; correctness is placement-free via agent fallback).
    // Group r's 8 shard blocks -> same presumed XCD (2 groups per XCD).
    const int mm   = bid >> 3;                   // 0..15 within presumed XCD
    const int c    = mm >> 1;                    // shard 0..7
    const int r    = (bid & 7) * 2 + (mm & 1);   // group 0..15
    const int rowbase = r * RG;
    const int jbase   = c * JC;
    const int myrow   = wave * 16 + l16;

    // double-buffered by step parity
    __shared__ __align__(16) f16 hg[2][RG][HH + 8];
    __shared__ __align__(16) f16 xsh[2][RG][II + 8];

    // ---- one-time: weight shards -> constant register B-fragments ----
    // B-frag: lane holds BT[n=lane&15][k=quad*8+j], j=0..7 (verified R0)
    f16x8 bf[16];   // W_hh shard, K=512 -> 16 k-steps
    f16x8 xbf[4];   // W_xh shard, K=128 -> 4 k-steps
    f16x8 bfo[2];   // W_out, this block's K-range [c*64, c*64+64)
    {
        const float* wp = Whh + (size_t)(jbase + myrow) * HH + quad * 8;
        #pragma unroll
        for (int ks = 0; ks < 16; ++ks) {
            float4 u = *(const float4*)(wp + ks * 32);
            float4 v = *(const float4*)(wp + ks * 32 + 4);
            f16x8 tv;
            tv[0]=(f16)u.x; tv[1]=(f16)u.y; tv[2]=(f16)u.z; tv[3]=(f16)u.w;
            tv[4]=(f16)v.x; tv[5]=(f16)v.y; tv[6]=(f16)v.z; tv[7]=(f16)v.w;
            bf[ks] = tv;
        }
        const float* wq = Wxh + (size_t)(jbase + myrow) * II + quad * 8;
        #pragma unroll
        for (int ks = 0; ks < 4; ++ks) {
            float4 u = *(const float4*)(wq + ks * 32);
            float4 v = *(const float4*)(wq + ks * 32 + 4);
            f16x8 tv;
            tv[0]=(f16)u.x; tv[1]=(f16)u.y; tv[2]=(f16)u.z; tv[3]=(f16)u.w;
            tv[4]=(f16)v.x; tv[5]=(f16)v.y; tv[6]=(f16)v.z; tv[7]=(f16)v.w;
            xbf[ks] = tv;
        }
        const float* wo = Wout + (size_t)myrow * HH + c * 64 + quad * 8;
        #pragma unroll
        for (int ks = 0; ks < 2; ++ks) {
            float4 u = *(const float4*)(wo + ks * 32);
            float4 v = *(const float4*)(wo + ks * 32 + 4);
            f16x8 tv;
            tv[0]=(f16)u.x; tv[1]=(f16)u.y; tv[2]=(f16)u.z; tv[3]=(f16)u.w;
            tv[4]=(f16)v.x; tv[5]=(f16)v.y; tv[6]=(f16)v.z; tv[7]=(f16)v.w;
            bfo[ks] = tv;
        }
    }
    const float biash = bh[jbase + myrow];
    const float biaso = (c == 0) ? bout[myrow] : 0.0f;

    // zero hg (t=0 uses h_0 = 0; buffer 1 fully written during iter 0)
    for (int p = tid; p < RG * (HH + 8); p += 256)
        ((unsigned int*)hg)[p] = 0u;

    // fp32 integrator state: lane owns h[m=quad*4+reg][jbase+myrow]
    float hreg[4] = {0.f, 0.f, 0.f, 0.f};

    // gather geometry: thread j8 owns u64-column j8 across 16 rows
    const int j8     = tid;          // 0..255
    const int gshard = j8 >> 5;      // producer shard of this u64-col

    // x prefetch for t=0
    float4 xpf0, xpf1;
    {
        int p0 = tid, p1 = tid + 256;
        xpf0 = ((const float4*)(x + ((size_t)(rowbase + (p0 >> 5)) * TT + 0) * II))[p0 & 31];
        xpf1 = ((const float4*)(x + ((size_t)(rowbase + (p1 >> 5)) * TT + 0) * II))[p1 & 31];
    }

    __syncthreads();

    for (int t = 0; t <= TT; ++t) {
        const int pcur = t & 1;

        // ---- stage x_t from prefetch regs into xsh[pcur] ----
        if (t < TT) {
            int p0 = tid, p1 = tid + 256;
            f16* d0 = &xsh[pcur][p0 >> 5][(p0 & 31) * 4];
            d0[0]=(f16)xpf0.x; d0[1]=(f16)xpf0.y; d0[2]=(f16)xpf0.z; d0[3]=(f16)xpf0.w;
            f16* d1 = &xsh[pcur][p1 >> 5][(p1 & 31) * 4];
            d1[0]=(f16)xpf1.x; d1[1]=(f16)xpf1.y; d1[2]=(f16)xpf1.z; d1[3]=(f16)xpf1.w;
        }
        // ---- issue x_{t+1} prefetch; poll waits absorb it ----
        if (t + 1 < TT) {
            int p0 = tid, p1 = tid + 256;
            xpf0 = ((const float4*)(x + ((size_t)(rowbase + (p0 >> 5)) * TT + (t + 1)) * II))[p0 & 31];
            xpf1 = ((const float4*)(x + ((size_t)(rowbase + (p1 >> 5)) * TT + (t + 1)) * II))[p1 & 31];
        }
        // ---- gather: poll tagged u64s with sc0 (L2-servable) loads ----
        if (t >= 1 && gshard != c) {
            const unsigned long long* src = hbuf
                + (size_t)pcur * (BB * HH / 2)
                + (size_t)rowbase * (HH / 2) + j8;
            const unsigned int tg = (unsigned)t;
            unsigned long long v0, v1, v2, v3, v4, v5, v6, v7;
            unsigned long long v8, v9, v10, v11, v12, v13, v14, v15;
            // batch issue rows 0-7 (no wait yet)
            asm volatile(
                "global_load_dwordx2 %0, %8, off sc0\n\t"
                "global_load_dwordx2 %1, %9, off sc0\n\t"
                "global_load_dwordx2 %2, %10, off sc0\n\t"
                "global_load_dwordx2 %3, %11, off sc0\n\t"
                "global_load_dwordx2 %4, %12, off sc0\n\t"
                "global_load_dwordx2 %5, %13, off sc0\n\t"
                "global_load_dwordx2 %6, %14, off sc0\n\t"
                "global_load_dwordx2 %7, %15, off sc0"
                : "=&v"(v0), "=&v"(v1), "=&v"(v2), "=&v"(v3),
                  "=&v"(v4), "=&v"(v5), "=&v"(v6), "=&v"(v7)
                : "v"((unsigned long long)(src)),
                  "v"((unsigned long long)(src + 1 * (HH / 2))),
                  "v"((unsigned long long)(src + 2 * (HH / 2))),
                  "v"((unsigned long long)(src + 3 * (HH / 2))),
                  "v"((unsigned long long)(src + 4 * (HH / 2))),
                  "v"((unsigned long long)(src + 5 * (HH / 2))),
                  "v"((unsigned long long)(src + 6 * (HH / 2))),
                  "v"((unsigned long long)(src + 7 * (HH / 2))));
            // batch issue rows 8-15, single wait; carry v0-v7 as inouts so
            // no use of them can be scheduled before the waitcnt completes
            asm volatile(
                "global_load_dwordx2 %0, %16, off sc0\n\t"
                "global_load_dwordx2 %1, %17, off sc0\n\t"
                "global_load_dwordx2 %2, %18, off sc0\n\t"
                "global_load_dwordx2 %3, %19, off sc0\n\t"
                "global_load_dwordx2 %4, %20, off sc0\n\t"
                "global_load_dwordx2 %5, %21, off sc0\n\t"
                "global_load_dwordx2 %6, %22, off sc0\n\t"
                "global_load_dwordx2 %7, %23, off sc0\n\t"
                "s_waitcnt vmcnt(0)"
                : "=&v"(v8), "=&v"(v9), "=&v"(v10), "=&v"(v11),
                  "=&v"(v12), "=&v"(v13), "=&v"(v14), "=&v"(v15),
                  "+v"(v0), "+v"(v1), "+v"(v2), "+v"(v3),
                  "+v"(v4), "+v"(v5), "+v"(v6), "+v"(v7)
                : "v"((unsigned long long)(src + 8 * (HH / 2))),
                  "v"((unsigned long long)(src + 9 * (HH / 2))),
                  "v"((unsigned long long)(src + 10 * (HH / 2))),
                  "v"((unsigned long long)(src + 11 * (HH / 2))),
                  "v"((unsigned long long)(src + 12 * (HH / 2))),
                  "v"((unsigned long long)(src + 13 * (HH / 2))),
                  "v"((unsigned long long)(src + 14 * (HH / 2))),
                  "v"((unsigned long long)(src + 15 * (HH / 2))));
            __builtin_amdgcn_sched_barrier(0);   // rule #18: fence reg uses

            unsigned long long vv[16] = {v0,v1,v2,v3,v4,v5,v6,v7,
                                         v8,v9,v10,v11,v12,v13,v14,v15};
            #pragma unroll
            for (int i = 0; i < 16; ++i) {
                unsigned long long w = vv[i];
                const unsigned long long* pp = src + (size_t)i * (HH / 2);
                int rr = 0;
                while ((unsigned)(w >> 32) != tg) {
                    ++rr;
                    if ((rr & 3) == 3) {
                        // guaranteed-progress round: R2's agent load (IF$)
                        w = __hip_atomic_load(pp, __ATOMIC_RELAXED,
                                              __HIP_MEMORY_SCOPE_AGENT);
                    } else {
                        asm volatile(
                            "global_load_dwordx2 %0, %1, off sc0\n\t"
                            "s_waitcnt vmcnt(0)"
                            : "=&v"(w) : "v"((unsigned long long)pp));
                    }
                }
                *(unsigned int*)&hg[pcur][i][j8 * 2] = (unsigned int)w;
            }
        }
        __syncthreads();   // B1: hg[pcur] + xsh[pcur] ready (only barrier/step)

        if (t < TT) {
            // pre = h_t.W_hh^T + x_t.W_xh^T + b_h
            f32x4 acc0 = {0.f,0.f,0.f,0.f}, acc1 = {0.f,0.f,0.f,0.f};
            #pragma unroll
            for (int ks = 0; ks < 16; ks += 2) {
                f16x8 a0 = *(const f16x8*)&hg[pcur][l16][ks * 32 + quad * 8];
                f16x8 a1 = *(const f16x8*)&hg[pcur][l16][(ks + 1) * 32 + quad * 8];
                acc0 = __builtin_amdgcn_mfma_f32_16x16x32_f16(a0, bf[ks], acc0, 0, 0, 0);
                acc1 = __builtin_amdgcn_mfma_f32_16x16x32_f16(a1, bf[ks + 1], acc1, 0, 0, 0);
            }
            #pragma unroll
            for (int ks = 0; ks < 4; ks += 2) {
                f16x8 a0 = *(const f16x8*)&xsh[pcur][l16][ks * 32 + quad * 8];
                f16x8 a1 = *(const f16x8*)&xsh[pcur][l16][(ks + 1) * 32 + quad * 8];
                acc0 = __builtin_amdgcn_mfma_f32_16x16x32_f16(a0, xbf[ks], acc0, 0, 0, 0);
                acc1 = __builtin_amdgcn_mfma_f32_16x16x32_f16(a1, xbf[ks + 1], acc1, 0, 0, 0);
            }
            // phi + leaky update; pack lane-pairs; fire-and-forget tagged u64
            unsigned long long* dst64 = hbuf + (size_t)((t + 1) & 1) * (BB * HH / 2);
            const unsigned long long tagw = ((unsigned long long)(unsigned)(t + 1)) << 32;
            unsigned int hb[4];
            #pragma unroll
            for (int reg = 0; reg < 4; ++reg) {
                float pre = acc0[reg] + acc1[reg] + biash;
                float z = 8.f * pre;
                float ph = (z > 20.f) ? pre : (__logf(1.f + __expf(z)) * 0.125f);
                float hn = 0.8f * hreg[reg] + 0.2f * ph;
                hreg[reg] = hn;
                hb[reg] = (unsigned int)__builtin_bit_cast(unsigned short, (f16)hn);
            }
            #pragma unroll
            for (int reg = 0; reg < 4; ++reg) {
                unsigned int ob = (unsigned int)__shfl_xor((int)hb[reg], 1, 64);
                if ((lane & 1) == 0) {
                    unsigned int pair = hb[reg] | (ob << 16);
                    size_t eidx = (size_t)(rowbase + quad * 4 + reg) * HH + jbase + myrow;
                    // agent/sc1 store (R2-proven): write-through local L2 -> IF$
                    __hip_atomic_store(dst64 + (eidx >> 1), tagw | (unsigned long long)pair,
                                       __ATOMIC_RELAXED, __HIP_MEMORY_SCOPE_AGENT);
                    // own-shard short-circuit into next-parity LDS buffer
                    *(unsigned int*)&hg[(t + 1) & 1][quad * 4 + reg][jbase + myrow] = pair;
                }
            }
        }

        // ---- readout partial: y_{t-1} += h_t[:, c*64:c*64+64] . W_out^T ----
        if (t >= 1) {
            f32x4 ya = {0.f,0.f,0.f,0.f};
            f16x8 a0 = *(const f16x8*)&hg[pcur][l16][c * 64 + quad * 8];
            f16x8 a1 = *(const f16x8*)&hg[pcur][l16][c * 64 + 32 + quad * 8];
            ya = __builtin_amdgcn_mfma_f32_16x16x32_f16(a0, bfo[0], ya, 0, 0, 0);
            ya = __builtin_amdgcn_mfma_f32_16x16x32_f16(a1, bfo[1], ya, 0, 0, 0);
            #pragma unroll
            for (int reg = 0; reg < 4; ++reg)
                atomicAdd(yout + ((size_t)(rowbase + quad * 4 + reg) * TT + (t - 1)) * OO + myrow,
                          ya[reg] + biaso);
        }
        // no B2: parity double-buffering; next iter's B1 is the only fence
    }
}

extern "C" void kernel_launch(void* const* d_in, const int* in_sizes, int n_in,
                              void* d_out, int out_size, void* d_ws, size_t ws_size,
                              hipStream_t stream)
{
    const float* x    = (const float*)d_in[0];
    const float* Wxh  = (const float*)d_in[1];
    const float* Whh  = (const float*)d_in[2];
    const float* bh   = (const float*)d_in[3];
    const float* Wout = (const float*)d_in[4];
    const float* bout = (const float*)d_in[5];
    float* yout = (float*)d_out;

    unsigned long long* hbuf = (unsigned long long*)d_ws;
    const size_t hbuf_bytes = (size_t)2 * BB * (HH / 2) * sizeof(unsigned long long); // 1 MB

    if (ws_size < hbuf_bytes) return;

    hipMemsetAsync(hbuf, 0, hbuf_bytes, stream);          // tags start 0; expected 1..512
    hipMemsetAsync(yout, 0, (size_t)out_size * sizeof(float), stream); // atomic targets

    // 128 blocks x 256 threads (1 block/CU, ~42KB LDS) -> all co-resident.
    eirnn_persist<<<dim3(NB), dim3(256), 0, stream>>>(
        x, Wxh, Whh, bh, Wout, bout, yout, hbuf);
}

// Round 6
// 1369.544 us; speedup vs baseline: 2.7957x; 1.4736x over previous
//
#include <hip/hip_runtime.h>

// EIRNN: B=256,T=512,I=128,H=512,O=64; alpha=0.2, softplus beta=8, thresh=20.
// R7 = R6's sc0 poll instruction + R2's BATCHED retry structure.
// R6 post-mortem: FETCH 1.18GB -> 170MB proved sc0 polls are served by the
// XCD L2 (sc1 stores write through into it), but dur went 1340 -> 2018us
// because the rewrite polled word-by-word: each stale word cost a full
// serial L2 RT (up to 16 sequential RTs/step). R7 re-batches: every retry
// round re-issues ALL 16 loads (two 8-wide asm blocks, one vmcnt(0)),
// checks all 16 tags, repeats -- ~1 pipelined L2 RT (~300cy) per round vs
// R2's ~700cy IF$ RT per round.
// Progress guarantee (placement-free, G16): every 4th round polls with the
// R2-proven agent load batch (sc0+sc1, IF$-served) -- a stale L2 line or
// cross-XCD placement costs at most 4x poll dilution, never a hang (R6
// passed on exactly this fallback).
// Tag monotonicity: within the step-t poll of buffer[t&1], a word's tag can
// only be t-2 or t (producer can't reach t+2 until every consumer finished
// this poll), so re-reading already-fresh words each round is safe.
// Everything else is byte-identical to R2/R6: tagged u64 {hi:tag, lo:2xf16}
// fire-and-forget sc1 stores, parity double-buffer, own-shard LDS
// short-circuit, K-split readout via atomicAdd, 128x256 launch.

#define BB 256
#define TT 512
#define II 128
#define HH 512
#define OO 64
#define RG 16   // batch rows per row-group
#define JC 64   // h-columns per shard block
#define NG 16   // row-groups
#define NC 8    // shard blocks per group
#define NB (NG * NC)

typedef _Float16 f16;
typedef f16 f16x8 __attribute__((ext_vector_type(8)));
typedef float f32x4 __attribute__((ext_vector_type(4)));

__global__ __launch_bounds__(256, 1)
void eirnn_persist(const float* __restrict__ x,
                   const float* __restrict__ Wxh,
                   const float* __restrict__ Whh,
                   const float* __restrict__ bh,
                   const float* __restrict__ Wout,
                   const float* __restrict__ bout,
                   float* __restrict__ yout,
                   unsigned long long* __restrict__ hbuf) // 2*(B*H/2) tagged u64
{
    const int tid  = threadIdx.x;
    const int bid  = blockIdx.x;
    const int wave = tid >> 6;
    const int lane = tid & 63;
    const int quad = lane >> 4;
    const int l16  = lane & 15;
    // XCD-clustered mapping (PERF HEURISTIC ONLY: presumed round-robin
    // dispatch xcd=bid&7; correctness is placement-free via agent fallback).
    const int mm   = bid >> 3;                   // 0..15 within presumed XCD
    const int c    = mm >> 1;                    // shard 0..7
    const int r    = (bid & 7) * 2 + (mm & 1);   // group 0..15
    const int rowbase = r * RG;
    const int jbase   = c * JC;
    const int myrow   = wave * 16 + l16;

    // double-buffered by step parity
    __shared__ __align__(16) f16 hg[2][RG][HH + 8];
    __shared__ __align__(16) f16 xsh[2][RG][II + 8];

    // ---- one-time: weight shards -> constant register B-fragments ----
    // B-frag: lane holds BT[n=lane&15][k=quad*8+j], j=0..7 (verified R0)
    f16x8 bf[16];   // W_hh shard, K=512 -> 16 k-steps
    f16x8 xbf[4];   // W_xh shard, K=128 -> 4 k-steps
    f16x8 bfo[2];   // W_out, this block's K-range [c*64, c*64+64)
    {
        const float* wp = Whh + (size_t)(jbase + myrow) * HH + quad * 8;
        #pragma unroll
        for (int ks = 0; ks < 16; ++ks) {
            float4 u = *(const float4*)(wp + ks * 32);
            float4 v = *(const float4*)(wp + ks * 32 + 4);
            f16x8 tv;
            tv[0]=(f16)u.x; tv[1]=(f16)u.y; tv[2]=(f16)u.z; tv[3]=(f16)u.w;
            tv[4]=(f16)v.x; tv[5]=(f16)v.y; tv[6]=(f16)v.z; tv[7]=(f16)v.w;
            bf[ks] = tv;
        }
        const float* wq = Wxh + (size_t)(jbase + myrow) * II + quad * 8;
        #pragma unroll
        for (int ks = 0; ks < 4; ++ks) {
            float4 u = *(const float4*)(wq + ks * 32);
            float4 v = *(const float4*)(wq + ks * 32 + 4);
            f16x8 tv;
            tv[0]=(f16)u.x; tv[1]=(f16)u.y; tv[2]=(f16)u.z; tv[3]=(f16)u.w;
            tv[4]=(f16)v.x; tv[5]=(f16)v.y; tv[6]=(f16)v.z; tv[7]=(f16)v.w;
            xbf[ks] = tv;
        }
        const float* wo = Wout + (size_t)myrow * HH + c * 64 + quad * 8;
        #pragma unroll
        for (int ks = 0; ks < 2; ++ks) {
            float4 u = *(const float4*)(wo + ks * 32);
            float4 v = *(const float4*)(wo + ks * 32 + 4);
            f16x8 tv;
            tv[0]=(f16)u.x; tv[1]=(f16)u.y; tv[2]=(f16)u.z; tv[3]=(f16)u.w;
            tv[4]=(f16)v.x; tv[5]=(f16)v.y; tv[6]=(f16)v.z; tv[7]=(f16)v.w;
            bfo[ks] = tv;
        }
    }
    const float biash = bh[jbase + myrow];
    const float biaso = (c == 0) ? bout[myrow] : 0.0f;

    // zero hg (t=0 uses h_0 = 0; buffer 1 fully written during iter 0)
    for (int p = tid; p < RG * (HH + 8); p += 256)
        ((unsigned int*)hg)[p] = 0u;

    // fp32 integrator state: lane owns h[m=quad*4+reg][jbase+myrow]
    float hreg[4] = {0.f, 0.f, 0.f, 0.f};

    // gather geometry: thread j8 owns u64-column j8 across 16 rows
    const int j8     = tid;          // 0..255
    const int gshard = j8 >> 5;      // producer shard of this u64-col

    // x prefetch for t=0
    float4 xpf0, xpf1;
    {
        int p0 = tid, p1 = tid + 256;
        xpf0 = ((const float4*)(x + ((size_t)(rowbase + (p0 >> 5)) * TT + 0) * II))[p0 & 31];
        xpf1 = ((const float4*)(x + ((size_t)(rowbase + (p1 >> 5)) * TT + 0) * II))[p1 & 31];
    }

    __syncthreads();

    for (int t = 0; t <= TT; ++t) {
        const int pcur = t & 1;

        // ---- stage x_t from prefetch regs into xsh[pcur] ----
        if (t < TT) {
            int p0 = tid, p1 = tid + 256;
            f16* d0 = &xsh[pcur][p0 >> 5][(p0 & 31) * 4];
            d0[0]=(f16)xpf0.x; d0[1]=(f16)xpf0.y; d0[2]=(f16)xpf0.z; d0[3]=(f16)xpf0.w;
            f16* d1 = &xsh[pcur][p1 >> 5][(p1 & 31) * 4];
            d1[0]=(f16)xpf1.x; d1[1]=(f16)xpf1.y; d1[2]=(f16)xpf1.z; d1[3]=(f16)xpf1.w;
        }
        // ---- issue x_{t+1} prefetch; poll waits absorb it ----
        if (t + 1 < TT) {
            int p0 = tid, p1 = tid + 256;
            xpf0 = ((const float4*)(x + ((size_t)(rowbase + (p0 >> 5)) * TT + (t + 1)) * II))[p0 & 31];
            xpf1 = ((const float4*)(x + ((size_t)(rowbase + (p1 >> 5)) * TT + (t + 1)) * II))[p1 & 31];
        }
        // ---- gather: batched poll rounds, sc0 (L2) with agent fallback ----
        if (t >= 1 && gshard != c) {
            const unsigned long long* src = hbuf
                + (size_t)pcur * (BB * HH / 2)
                + (size_t)rowbase * (HH / 2) + j8;
            const unsigned int tg = (unsigned)t;
            unsigned long long v0, v1, v2, v3, v4, v5, v6, v7;
            unsigned long long v8, v9, v10, v11, v12, v13, v14, v15;
            int round = 0;
            for (;;) {
                if ((round & 3) != 3) {
                    // sc0 batch: L1-bypass, L2-servable, 16 loads in flight
                    asm volatile(
                        "global_load_dwordx2 %0, %8, off sc0\n\t"
                        "global_load_dwordx2 %1, %9, off sc0\n\t"
                        "global_load_dwordx2 %2, %10, off sc0\n\t"
                        "global_load_dwordx2 %3, %11, off sc0\n\t"
                        "global_load_dwordx2 %4, %12, off sc0\n\t"
                        "global_load_dwordx2 %5, %13, off sc0\n\t"
                        "global_load_dwordx2 %6, %14, off sc0\n\t"
                        "global_load_dwordx2 %7, %15, off sc0"
                        : "=&v"(v0), "=&v"(v1), "=&v"(v2), "=&v"(v3),
                          "=&v"(v4), "=&v"(v5), "=&v"(v6), "=&v"(v7)
                        : "v"((unsigned long long)(src)),
                          "v"((unsigned long long)(src + 1 * (HH / 2))),
                          "v"((unsigned long long)(src + 2 * (HH / 2))),
                          "v"((unsigned long long)(src + 3 * (HH / 2))),
                          "v"((unsigned long long)(src + 4 * (HH / 2))),
                          "v"((unsigned long long)(src + 5 * (HH / 2))),
                          "v"((unsigned long long)(src + 6 * (HH / 2))),
                          "v"((unsigned long long)(src + 7 * (HH / 2))));
                    asm volatile(
                        "global_load_dwordx2 %0, %16, off sc0\n\t"
                        "global_load_dwordx2 %1, %17, off sc0\n\t"
                        "global_load_dwordx2 %2, %18, off sc0\n\t"
                        "global_load_dwordx2 %3, %19, off sc0\n\t"
                        "global_load_dwordx2 %4, %20, off sc0\n\t"
                        "global_load_dwordx2 %5, %21, off sc0\n\t"
                        "global_load_dwordx2 %6, %22, off sc0\n\t"
                        "global_load_dwordx2 %7, %23, off sc0\n\t"
                        "s_waitcnt vmcnt(0)"
                        : "=&v"(v8), "=&v"(v9), "=&v"(v10), "=&v"(v11),
                          "=&v"(v12), "=&v"(v13), "=&v"(v14), "=&v"(v15),
                          "+v"(v0), "+v"(v1), "+v"(v2), "+v"(v3),
                          "+v"(v4), "+v"(v5), "+v"(v6), "+v"(v7)
                        : "v"((unsigned long long)(src + 8 * (HH / 2))),
                          "v"((unsigned long long)(src + 9 * (HH / 2))),
                          "v"((unsigned long long)(src + 10 * (HH / 2))),
                          "v"((unsigned long long)(src + 11 * (HH / 2))),
                          "v"((unsigned long long)(src + 12 * (HH / 2))),
                          "v"((unsigned long long)(src + 13 * (HH / 2))),
                          "v"((unsigned long long)(src + 14 * (HH / 2))),
                          "v"((unsigned long long)(src + 15 * (HH / 2))));
                    __builtin_amdgcn_sched_barrier(0);   // rule #18
                } else {
                    // guaranteed-progress round: R2's agent loads (IF$-served)
                    v0  = __hip_atomic_load(src +  0 * (HH / 2), __ATOMIC_RELAXED, __HIP_MEMORY_SCOPE_AGENT);
                    v1  = __hip_atomic_load(src +  1 * (HH / 2), __ATOMIC_RELAXED, __HIP_MEMORY_SCOPE_AGENT);
                    v2  = __hip_atomic_load(src +  2 * (HH / 2), __ATOMIC_RELAXED, __HIP_MEMORY_SCOPE_AGENT);
                    v3  = __hip_atomic_load(src +  3 * (HH / 2), __ATOMIC_RELAXED, __HIP_MEMORY_SCOPE_AGENT);
                    v4  = __hip_atomic_load(src +  4 * (HH / 2), __ATOMIC_RELAXED, __HIP_MEMORY_SCOPE_AGENT);
                    v5  = __hip_atomic_load(src +  5 * (HH / 2), __ATOMIC_RELAXED, __HIP_MEMORY_SCOPE_AGENT);
                    v6  = __hip_atomic_load(src +  6 * (HH / 2), __ATOMIC_RELAXED, __HIP_MEMORY_SCOPE_AGENT);
                    v7  = __hip_atomic_load(src +  7 * (HH / 2), __ATOMIC_RELAXED, __HIP_MEMORY_SCOPE_AGENT);
                    v8  = __hip_atomic_load(src +  8 * (HH / 2), __ATOMIC_RELAXED, __HIP_MEMORY_SCOPE_AGENT);
                    v9  = __hip_atomic_load(src +  9 * (HH / 2), __ATOMIC_RELAXED, __HIP_MEMORY_SCOPE_AGENT);
                    v10 = __hip_atomic_load(src + 10 * (HH / 2), __ATOMIC_RELAXED, __HIP_MEMORY_SCOPE_AGENT);
                    v11 = __hip_atomic_load(src + 11 * (HH / 2), __ATOMIC_RELAXED, __HIP_MEMORY_SCOPE_AGENT);
                    v12 = __hip_atomic_load(src + 12 * (HH / 2), __ATOMIC_RELAXED, __HIP_MEMORY_SCOPE_AGENT);
                    v13 = __hip_atomic_load(src + 13 * (HH / 2), __ATOMIC_RELAXED, __HIP_MEMORY_SCOPE_AGENT);
                    v14 = __hip_atomic_load(src + 14 * (HH / 2), __ATOMIC_RELAXED, __HIP_MEMORY_SCOPE_AGENT);
                    v15 = __hip_atomic_load(src + 15 * (HH / 2), __ATOMIC_RELAXED, __HIP_MEMORY_SCOPE_AGENT);
                }
                // all-16 tag check (tags can't pass tg within this poll)
                bool ok = ((unsigned)(v0  >> 32) == tg) & ((unsigned)(v1  >> 32) == tg)
                        & ((unsigned)(v2  >> 32) == tg) & ((unsigned)(v3  >> 32) == tg)
                        & ((unsigned)(v4  >> 32) == tg) & ((unsigned)(v5  >> 32) == tg)
                        & ((unsigned)(v6  >> 32) == tg) & ((unsigned)(v7  >> 32) == tg)
                        & ((unsigned)(v8  >> 32) == tg) & ((unsigned)(v9  >> 32) == tg)
                        & ((unsigned)(v10 >> 32) == tg) & ((unsigned)(v11 >> 32) == tg)
                        & ((unsigned)(v12 >> 32) == tg) & ((unsigned)(v13 >> 32) == tg)
                        & ((unsigned)(v14 >> 32) == tg) & ((unsigned)(v15 >> 32) == tg);
                if (ok) break;
                ++round;
            }
            *(unsigned int*)&hg[pcur][ 0][j8 * 2] = (unsigned int)v0;
            *(unsigned int*)&hg[pcur][ 1][j8 * 2] = (unsigned int)v1;
            *(unsigned int*)&hg[pcur][ 2][j8 * 2] = (unsigned int)v2;
            *(unsigned int*)&hg[pcur][ 3][j8 * 2] = (unsigned int)v3;
            *(unsigned int*)&hg[pcur][ 4][j8 * 2] = (unsigned int)v4;
            *(unsigned int*)&hg[pcur][ 5][j8 * 2] = (unsigned int)v5;
            *(unsigned int*)&hg[pcur][ 6][j8 * 2] = (unsigned int)v6;
            *(unsigned int*)&hg[pcur][ 7][j8 * 2] = (unsigned int)v7;
            *(unsigned int*)&hg[pcur][ 8][j8 * 2] = (unsigned int)v8;
            *(unsigned int*)&hg[pcur][ 9][j8 * 2] = (unsigned int)v9;
            *(unsigned int*)&hg[pcur][10][j8 * 2] = (unsigned int)v10;
            *(unsigned int*)&hg[pcur][11][j8 * 2] = (unsigned int)v11;
            *(unsigned int*)&hg[pcur][12][j8 * 2] = (unsigned int)v12;
            *(unsigned int*)&hg[pcur][13][j8 * 2] = (unsigned int)v13;
            *(unsigned int*)&hg[pcur][14][j8 * 2] = (unsigned int)v14;
            *(unsigned int*)&hg[pcur][15][j8 * 2] = (unsigned int)v15;
        }
        __syncthreads();   // B1: hg[pcur] + xsh[pcur] ready (only barrier/step)

        if (t < TT) {
            // pre = h_t.W_hh^T + x_t.W_xh^T + b_h
            f32x4 acc0 = {0.f,0.f,0.f,0.f}, acc1 = {0.f,0.f,0.f,0.f};
            #pragma unroll
            for (int ks = 0; ks < 16; ks += 2) {
                f16x8 a0 = *(const f16x8*)&hg[pcur][l16][ks * 32 + quad * 8];
                f16x8 a1 = *(const f16x8*)&hg[pcur][l16][(ks + 1) * 32 + quad * 8];
                acc0 = __builtin_amdgcn_mfma_f32_16x16x32_f16(a0, bf[ks], acc0, 0, 0, 0);
                acc1 = __builtin_amdgcn_mfma_f32_16x16x32_f16(a1, bf[ks + 1], acc1, 0, 0, 0);
            }
            #pragma unroll
            for (int ks = 0; ks < 4; ks += 2) {
                f16x8 a0 = *(const f16x8*)&xsh[pcur][l16][ks * 32 + quad * 8];
                f16x8 a1 = *(const f16x8*)&xsh[pcur][l16][(ks + 1) * 32 + quad * 8];
                acc0 = __builtin_amdgcn_mfma_f32_16x16x32_f16(a0, xbf[ks], acc0, 0, 0, 0);
                acc1 = __builtin_amdgcn_mfma_f32_16x16x32_f16(a1, xbf[ks + 1], acc1, 0, 0, 0);
            }
            // phi + leaky update; pack lane-pairs; fire-and-forget tagged u64
            unsigned long long* dst64 = hbuf + (size_t)((t + 1) & 1) * (BB * HH / 2);
            const unsigned long long tagw = ((unsigned long long)(unsigned)(t + 1)) << 32;
            unsigned int hb[4];
            #pragma unroll
            for (int reg = 0; reg < 4; ++reg) {
                float pre = acc0[reg] + acc1[reg] + biash;
                float z = 8.f * pre;
                float ph = (z > 20.f) ? pre : (__logf(1.f + __expf(z)) * 0.125f);
                float hn = 0.8f * hreg[reg] + 0.2f * ph;
                hreg[reg] = hn;
                hb[reg] = (unsigned int)__builtin_bit_cast(unsigned short, (f16)hn);
            }
            #pragma unroll
            for (int reg = 0; reg < 4; ++reg) {
                unsigned int ob = (unsigned int)__shfl_xor((int)hb[reg], 1, 64);
                if ((lane & 1) == 0) {
                    unsigned int pair = hb[reg] | (ob << 16);
                    size_t eidx = (size_t)(rowbase + quad * 4 + reg) * HH + jbase + myrow;
                    // agent/sc1 store (R2-proven): write-through local L2 -> IF$
                    __hip_atomic_store(dst64 + (eidx >> 1), tagw | (unsigned long long)pair,
                                       __ATOMIC_RELAXED, __HIP_MEMORY_SCOPE_AGENT);
                    // own-shard short-circuit into next-parity LDS buffer
                    *(unsigned int*)&hg[(t + 1) & 1][quad * 4 + reg][jbase + myrow] = pair;
                }
            }
        }

        // ---- readout partial: y_{t-1} += h_t[:, c*64:c*64+64] . W_out^T ----
        if (t >= 1) {
            f32x4 ya = {0.f,0.f,0.f,0.f};
            f16x8 a0 = *(const f16x8*)&hg[pcur][l16][c * 64 + quad * 8];
            f16x8 a1 = *(const f16x8*)&hg[pcur][l16][c * 64 + 32 + quad * 8];
            ya = __builtin_amdgcn_mfma_f32_16x16x32_f16(a0, bfo[0], ya, 0, 0, 0);
            ya = __builtin_amdgcn_mfma_f32_16x16x32_f16(a1, bfo[1], ya, 0, 0, 0);
            #pragma unroll
            for (int reg = 0; reg < 4; ++reg)
                atomicAdd(yout + ((size_t)(rowbase + quad * 4 + reg) * TT + (t - 1)) * OO + myrow,
                          ya[reg] + biaso);
        }
        // no B2: parity double-buffering; next iter's B1 is the only fence
    }
}

extern "C" void kernel_launch(void* const* d_in, const int* in_sizes, int n_in,
                              void* d_out, int out_size, void* d_ws, size_t ws_size,
                              hipStream_t stream)
{
    const float* x    = (const float*)d_in[0];
    const float* Wxh  = (const float*)d_in[1];
    const float* Whh  = (const float*)d_in[2];
    const float* bh   = (const float*)d_in[3];
    const float* Wout = (const float*)d_in[4];
    const float* bout = (const float*)d_in[5];
    float* yout = (float*)d_out;

    unsigned long long* hbuf = (unsigned long long*)d_ws;
    const size_t hbuf_bytes = (size_t)2 * BB * (HH / 2) * sizeof(unsigned long long); // 1 MB

    if (ws_size < hbuf_bytes) return;

    hipMemsetAsync(hbuf, 0, hbuf_bytes, stream);          // tags start 0; expected 1..512
    hipMemsetAsync(yout, 0, (size_t)out_size * sizeof(float), stream); // atomic targets

    // 128 blocks x 256 threads (1 block/CU, ~42KB LDS) -> all co-resident.
    eirnn_persist<<<dim3(NB), dim3(256), 0, stream>>>(
        x, Wxh, Whh, bh, Wout, bout, yout, hbuf);
}